// Round 7
// baseline (446.403 us; speedup 1.0000x reference)
//
#include <hip/hip_runtime.h>
#include <hip/hip_bf16.h>
#include <cstdint>
#include <cstddef>

typedef __bf16 bf16;
typedef bf16 bf16x4 __attribute__((ext_vector_type(4)));
typedef bf16 bf16x8 __attribute__((ext_vector_type(8)));
typedef float floatx4 __attribute__((ext_vector_type(4)));

#define MFMA16(a, b, c) __builtin_amdgcn_mfma_f32_16x16x32_bf16((a), (b), (c), 0, 0, 0)

// log2(e)/8: S is the RAW k.q dot; softmax uses exp(S/8) = exp2(S*K2)
#define K2 0.18033688011112042f

__device__ __forceinline__ void async16(const void* g, void* l) {
    __builtin_amdgcn_global_load_lds((const __attribute__((address_space(1))) void*)g,
                                     (__attribute__((address_space(3))) void*)l,
                                     16, 0, 0);
}

// swizzled 64x64 bf16 tile stage + reads (attention kernels)
__device__ __forceinline__ void stage64s(const bf16* g0, int ldg, bf16* lds, int wave, int lane) {
#pragma unroll
    for (int i = 0; i < 2; ++i) {
        int r0 = wave * 16 + i * 8;  // wave-uniform
        async16(g0 + (size_t)(r0 + (lane >> 3)) * ldg + ((lane & 7) ^ (lane >> 3)) * 8,
                lds + r0 * 64);
    }
}
__device__ __forceinline__ bf16x8 rd64(const bf16* t, int row, int chunk) {
    return *(const bf16x8*)&t[row * 64 + ((chunk ^ (row & 7)) * 8)];
}

// ---------------------------------------------------------------------------
// Fused fp32->bf16 convert
// ---------------------------------------------------------------------------
__global__ __launch_bounds__(256) void cvt_all(const float* __restrict__ x,
                                               const float* __restrict__ WQ,
                                               const float* __restrict__ WK,
                                               const float* __restrict__ WV,
                                               const float* __restrict__ WO,
                                               const float* __restrict__ Win,
                                               const float* __restrict__ Wout,
                                               bf16* __restrict__ xb,
                                               bf16* __restrict__ wqkv,
                                               bf16* __restrict__ wo,
                                               bf16* __restrict__ win,
                                               bf16* __restrict__ wout) {
    int blk = blockIdx.x;
    const float* src;
    bf16* dst;
    int off;
    if (blk < 1024)      { src = WQ;   dst = wqkv;           off = blk; }
    else if (blk < 2048) { src = WK;   dst = wqkv + 1048576; off = blk - 1024; }
    else if (blk < 3072) { src = WV;   dst = wqkv + 2097152; off = blk - 2048; }
    else if (blk < 4096) { src = WO;   dst = wo;             off = blk - 3072; }
    else if (blk < 8192) { src = Win;  dst = win;            off = blk - 4096; }
    else if (blk < 12288){ src = Wout; dst = wout;           off = blk - 8192; }
    else                 { src = x;    dst = xb;             off = blk - 12288; }
    int i = off * 1024 + threadIdx.x * 4;
    float4 v = *(const float4*)(src + i);
    bf16x4 o = {(bf16)v.x, (bf16)v.y, (bf16)v.z, (bf16)v.w};
    *(bf16x4*)(dst + i) = o;
}

// ---------------------------------------------------------------------------
// bf16 GEMM, C[M,N] = A[M,K]*B[N,K]^T. m97-shape: 128xNT tile, BK=64,
// single-buffered LDS, 2 barriers/iter. blockIdx.z = K-split index (each
// split covers K/gridDim.z).
// EPI 0: bf16 store; 1: +res -> fp32+bf16; 2: relu(+bias) -> bf16;
// EPI 3: +bias+Cf -> fp32 (single split only);
// EPI 4: atomicAdd(Cf, acc + (split0 ? bias : 0))  [split-K]
// ---------------------------------------------------------------------------
template <int EPI, int NT>
__global__ __launch_bounds__(256) void gemm97(const bf16* __restrict__ A, int lda,
                                              const bf16* __restrict__ B, int ldb, int K,
                                              float* __restrict__ Cf, bf16* __restrict__ Cb,
                                              int ldc, const float* __restrict__ bias,
                                              const float* __restrict__ res) {
    constexpr int NACC = NT / 32;  // 4 (NT=128) or 2 (NT=64)
    __shared__ __align__(16) bf16 As[128 * 64];
    __shared__ __align__(16) bf16 Bs[NT * 64];
    const int tid = threadIdx.x, wave = tid >> 6, lane = tid & 63;
    const int m0 = blockIdx.y * 128, n0 = blockIdx.x * NT;
    const int wm = (wave >> 1) * 64, wn = (wave & 1) * (NT / 2);
    const int col = lane & 15, quad = lane >> 4;
    const int klen = K / (int)gridDim.z;
    const int kbeg = blockIdx.z * klen, kend = kbeg + klen;

    floatx4 acc[4][NACC];
#pragma unroll
    for (int mi = 0; mi < 4; ++mi)
#pragma unroll
        for (int ni = 0; ni < NACC; ++ni) acc[mi][ni] = (floatx4){0.f, 0.f, 0.f, 0.f};

    const int rsub = lane >> 3, csub = (lane & 7) * 8;

    for (int k0 = kbeg; k0 < kend; k0 += 64) {
        __syncthreads();  // prior ds_reads of As/Bs done before overwrite
#pragma unroll
        for (int i = 0; i < 4; ++i) {
            int r0 = wave * 32 + i * 8;  // wave-uniform; instr covers 8 rows of 128B
            async16(A + (size_t)(m0 + r0 + rsub) * lda + k0 + csub, As + r0 * 64);
        }
        if constexpr (NT == 128) {
#pragma unroll
            for (int i = 0; i < 4; ++i) {
                int r0 = wave * 32 + i * 8;
                async16(B + (size_t)(n0 + r0 + rsub) * ldb + k0 + csub, Bs + r0 * 64);
            }
        } else {
#pragma unroll
            for (int i = 0; i < 2; ++i) {
                int r0 = wave * 16 + i * 8;
                async16(B + (size_t)(n0 + r0 + rsub) * ldb + k0 + csub, Bs + r0 * 64);
            }
        }
        __syncthreads();  // drains vmcnt: tiles arrived

#pragma unroll
        for (int ks = 0; ks < 2; ++ks) {
            bf16x8 af[4], bfr[NACC];
#pragma unroll
            for (int mi = 0; mi < 4; ++mi)
                af[mi] = *(const bf16x8*)&As[(wm + mi * 16 + col) * 64 + ks * 32 + quad * 8];
#pragma unroll
            for (int ni = 0; ni < NACC; ++ni)
                bfr[ni] = *(const bf16x8*)&Bs[(wn + ni * 16 + col) * 64 + ks * 32 + quad * 8];
#pragma unroll
            for (int mi = 0; mi < 4; ++mi)
#pragma unroll
                for (int ni = 0; ni < NACC; ++ni)
                    acc[mi][ni] = MFMA16(af[mi], bfr[ni], acc[mi][ni]);
        }
    }

#pragma unroll
    for (int mi = 0; mi < 4; ++mi)
#pragma unroll
        for (int ni = 0; ni < NACC; ++ni)
#pragma unroll
            for (int r = 0; r < 4; ++r) {
                int row = m0 + wm + mi * 16 + quad * 4 + r;
                int cc = n0 + wn + ni * 16 + col;
                size_t idx = (size_t)row * ldc + cc;
                float v = acc[mi][ni][r];
                if constexpr (EPI == 0) {
                    Cb[idx] = (bf16)v;
                } else if constexpr (EPI == 1) {
                    v += res[idx];
                    Cf[idx] = v;
                    Cb[idx] = (bf16)v;
                } else if constexpr (EPI == 2) {
                    v += bias[cc];
                    v = fmaxf(v, 0.f);
                    Cb[idx] = (bf16)v;
                } else if constexpr (EPI == 3) {
                    v += bias[cc] + Cf[idx];
                    Cf[idx] = v;
                } else {
                    if (blockIdx.z == 0) v += bias[cc];
                    atomicAdd(&Cf[idx], v);
                }
            }
}

// ---------------------------------------------------------------------------
// Transpose V
// ---------------------------------------------------------------------------
__global__ __launch_bounds__(256) void transpose_v(const bf16* __restrict__ qkv,
                                                   bf16* __restrict__ vt) {
    __shared__ bf16 t[64][65];
    const int bh = blockIdx.y, ct = blockIdx.x;
    const int b = bh >> 4, a = bh & 15;
    for (int idx = threadIdx.x; idx < 4096; idx += 256) {
        int c = idx >> 6, h = idx & 63;
        t[h][c] = qkv[(size_t)(b * 2048 + ct * 64 + c) * 3072 + 2048 + a * 64 + h];
    }
    __syncthreads();
    for (int idx = threadIdx.x; idx < 4096; idx += 256) {
        int h = idx >> 6, c = idx & 63;
        vt[(size_t)(bh * 64 + h) * 2048 + ct * 64 + c] = t[h][c];
    }
}

// ---------------------------------------------------------------------------
// Attention pass 1: l_c = sum_{C<=c} exp(S/8). Stores mp2[c] = log2(l_c).
// ---------------------------------------------------------------------------
__global__ __launch_bounds__(256) void attn_stats(const bf16* __restrict__ qkv,
                                                  float* __restrict__ mp2) {
    __shared__ __align__(16) bf16 Kt[64 * 64];
    __shared__ __align__(16) bf16 Qt[3][64 * 64];
    const int xx = blockIdx.x;
    const int ct = (xx & 1) ? (31 - (xx >> 1)) : (xx >> 1);
    const int bh = blockIdx.y;
    const int b = bh >> 4, a = bh & 15;
    const int tid = threadIdx.x, wave = tid >> 6, lane = tid & 63;
    const int col = lane & 15, quad = lane >> 4;
    const bf16* base = qkv + (size_t)b * 2048 * 3072;

    stage64s(base + (size_t)ct * 64 * 3072 + 1024 + a * 64, 3072, Kt, wave, lane);
    stage64s(base + a * 64, 3072, Qt[0], wave, lane);
    if (ct >= 1) stage64s(base + (size_t)1 * 64 * 3072 + a * 64, 3072, Qt[1], wave, lane);

    float lrun[4] = {0.f, 0.f, 0.f, 0.f};
    bf16x8 a0, a1;

    for (int Ct = 0; Ct <= ct; ++Ct) {
        if (Ct < ct) asm volatile("s_waitcnt vmcnt(2)" ::: "memory");
        else         asm volatile("s_waitcnt vmcnt(0)" ::: "memory");
        __builtin_amdgcn_s_barrier();
        if (Ct + 2 <= ct)
            stage64s(base + (size_t)(Ct + 2) * 64 * 3072 + a * 64, 3072,
                     Qt[(Ct + 2) % 3], wave, lane);
        if (Ct == 0) {
            a0 = rd64(Kt, wave * 16 + col, quad);
            a1 = rd64(Kt, wave * 16 + col, quad + 4);
        }
        const bf16* q = Qt[Ct % 3];
#pragma unroll
        for (int nt = 0; nt < 4; ++nt) {
            bf16x8 b0 = rd64(q, nt * 16 + col, quad);
            bf16x8 b1 = rd64(q, nt * 16 + col, quad + 4);
            floatx4 sacc = (floatx4){0.f, 0.f, 0.f, 0.f};
            sacc = MFMA16(a0, b0, sacc);
            sacc = MFMA16(a1, b1, sacc);
#pragma unroll
            for (int r = 0; r < 4; ++r) {
                float e = __builtin_amdgcn_exp2f(sacc[r] * K2);
                if (Ct == ct && (nt * 16 + col) > (wave * 16 + quad * 4 + r)) e = 0.f;
                lrun[r] += e;
            }
        }
    }
#pragma unroll
    for (int r = 0; r < 4; ++r) {
        float t = lrun[r];
        t += __shfl_xor(t, 1);
        t += __shfl_xor(t, 2);
        t += __shfl_xor(t, 4);
        t += __shfl_xor(t, 8);
        lrun[r] = t;
    }
    if (col == 0) {
#pragma unroll
        for (int r = 0; r < 4; ++r) {
            int c = ct * 64 + wave * 16 + quad * 4 + r;
            mp2[(size_t)bh * 2048 + c] = __builtin_amdgcn_logf(lrun[r]);
        }
    }
}

// ---------------------------------------------------------------------------
// Attention pass 2: z[C][h] = sum_{c>=C} P[c][C]*v[c][h]
// ---------------------------------------------------------------------------
__global__ __launch_bounds__(256) void attn_av(const bf16* __restrict__ qkv,
                                               const bf16* __restrict__ vt,
                                               const float* __restrict__ mp2,
                                               bf16* __restrict__ zb) {
    __shared__ __align__(16) bf16 Qt[64 * 64];
    __shared__ __align__(16) bf16 Kt[3][64 * 64];
    __shared__ __align__(16) bf16 Vt[3][64 * 64];
    __shared__ __align__(16) bf16 Pt[64 * 72];
    __shared__ __align__(16) float mpS[2048];
    const int xx = blockIdx.x;
    const int Ctile = (xx & 1) ? (31 - (xx >> 1)) : (xx >> 1);
    const int bh = blockIdx.y;
    const int b = bh >> 4, a = bh & 15;
    const int tid = threadIdx.x, wave = tid >> 6, lane = tid & 63;
    const int col = lane & 15, quad = lane >> 4;
    const bf16* base = qkv + (size_t)b * 2048 * 3072;
    const float* mpb = mp2 + (size_t)bh * 2048;
    const int niter = 32 - Ctile;

    stage64s(base + (size_t)Ctile * 64 * 3072 + a * 64, 3072, Qt, wave, lane);
    {
        int nb = niter * 256;
#pragma unroll
        for (int i = 0; i < 2; ++i) {
            int off = (i * 4 + wave) * 1024;  // wave-uniform
            if (off < nb)
                async16((const char*)(mpb + Ctile * 64) + off + lane * 16,
                        (char*)mpS + off);
        }
    }
    stage64s(base + (size_t)Ctile * 64 * 3072 + 1024 + a * 64, 3072, Kt[0], wave, lane);
    stage64s(vt + (size_t)bh * 64 * 2048 + Ctile * 64, 2048, Vt[0], wave, lane);
    if (niter > 1) {
        stage64s(base + (size_t)(Ctile + 1) * 64 * 3072 + 1024 + a * 64, 3072, Kt[1], wave, lane);
        stage64s(vt + (size_t)bh * 64 * 2048 + (Ctile + 1) * 64, 2048, Vt[1], wave, lane);
    }

    floatx4 zacc[4];
#pragma unroll
    for (int mi = 0; mi < 4; ++mi) zacc[mi] = (floatx4){0.f, 0.f, 0.f, 0.f};
    bf16x8 qf0[4], qf1[4];

    for (int i = 0; i < niter; ++i) {
        const int ct = Ctile + i;
        if (i + 1 < niter) asm volatile("s_waitcnt vmcnt(4)" ::: "memory");
        else               asm volatile("s_waitcnt vmcnt(0)" ::: "memory");
        __builtin_amdgcn_s_barrier();
        if (i + 2 < niter) {
            stage64s(base + (size_t)(ct + 2) * 64 * 3072 + 1024 + a * 64, 3072,
                     Kt[(i + 2) % 3], wave, lane);
            stage64s(vt + (size_t)bh * 64 * 2048 + (ct + 2) * 64, 2048,
                     Vt[(i + 2) % 3], wave, lane);
        }
        if (i == 0) {
#pragma unroll
            for (int nt = 0; nt < 4; ++nt) {
                qf0[nt] = rd64(Qt, nt * 16 + col, quad);
                qf1[nt] = rd64(Qt, nt * 16 + col, quad + 4);
            }
        }
        const bf16* kt = Kt[i % 3];
        const bf16* vts = Vt[i % 3];
        bf16x8 a0 = rd64(kt, wave * 16 + col, quad);
        bf16x8 a1 = rd64(kt, wave * 16 + col, quad + 4);
        float4 mpv = *(const float4*)&mpS[i * 64 + wave * 16 + quad * 4];
        const float mpl[4] = {mpv.x, mpv.y, mpv.z, mpv.w};

#pragma unroll
        for (int nt = 0; nt < 4; ++nt) {
            floatx4 sacc = (floatx4){0.f, 0.f, 0.f, 0.f};
            sacc = MFMA16(a0, qf0[nt], sacc);
            sacc = MFMA16(a1, qf1[nt], sacc);
            bf16x4 pv;
#pragma unroll
            for (int r = 0; r < 4; ++r) {
                float p;
                if (ct == Ctile && (nt * 16 + col) > (wave * 16 + quad * 4 + r))
                    p = 0.f;
                else
                    p = __builtin_amdgcn_exp2f(sacc[r] * K2 - mpl[r]);
                pv[r] = (bf16)p;
            }
            *(bf16x4*)&Pt[(nt * 16 + col) * 72 + wave * 16 + quad * 4] = pv;
        }
        asm volatile("s_waitcnt lgkmcnt(0)" ::: "memory");
        __builtin_amdgcn_s_barrier();

        bf16x8 v0 = rd64(vts, wave * 16 + col, quad);
        bf16x8 v1 = rd64(vts, wave * 16 + col, quad + 4);
#pragma unroll
        for (int mi = 0; mi < 4; ++mi) {
            bf16x8 p0 = *(const bf16x8*)&Pt[(mi * 16 + col) * 72 + quad * 8];
            bf16x8 p1 = *(const bf16x8*)&Pt[(mi * 16 + col) * 72 + 32 + quad * 8];
            zacc[mi] = MFMA16(p0, v0, zacc[mi]);
            zacc[mi] = MFMA16(p1, v1, zacc[mi]);
        }
    }
#pragma unroll
    for (int mi = 0; mi < 4; ++mi)
#pragma unroll
        for (int r = 0; r < 4; ++r) {
            int Cg = Ctile * 64 + mi * 16 + quad * 4 + r;
            zb[(size_t)(b * 2048 + Cg) * 1024 + a * 64 + wave * 16 + col] =
                (bf16)zacc[mi][r];
        }
}

// ---------------------------------------------------------------------------
// Host launcher
// ---------------------------------------------------------------------------
extern "C" void kernel_launch(void* const* d_in, const int* in_sizes, int n_in,
                              void* d_out, int out_size, void* d_ws, size_t ws_size,
                              hipStream_t stream) {
    (void)in_sizes; (void)n_in; (void)out_size; (void)ws_size;
    const float* x    = (const float*)d_in[0];
    const float* WK   = (const float*)d_in[1];
    const float* WQ   = (const float*)d_in[2];
    const float* WV   = (const float*)d_in[3];
    const float* WO   = (const float*)d_in[4];
    const float* Win  = (const float*)d_in[5];
    const float* bin  = (const float*)d_in[6];
    const float* Wout = (const float*)d_in[7];
    const float* bout = (const float*)d_in[8];
    float* out = (float*)d_out;

    char* ws = (char*)d_ws;
    bf16*  xb   = (bf16*)(ws + 0);          //  8 MB
    bf16*  wqkv = (bf16*)(ws + 8388608);    //  6 MB
    bf16*  wo   = (bf16*)(ws + 14680064);   //  2 MB
    bf16*  win  = (bf16*)(ws + 16777216);   //  8 MB
    bf16*  wout = (bf16*)(ws + 25165824);   //  8 MB
    bf16*  qkvb = (bf16*)(ws + 33554432);   // 24 MB
    bf16*  vtb  = (bf16*)(ws + 58720256);   //  8 MB
    float* mst  = (float*)(ws + 67108864);  // 256 KB (mp2)
    bf16*  zbuf = (bf16*)(ws + 67633152);   //  8 MB
    bf16*  xmid = (bf16*)(ws + 76021760);   //  8 MB
    bf16*  hbuf = (bf16*)(ws + 84410368);   // 32 MB

    cvt_all<<<16384, 256, 0, stream>>>(x, WQ, WK, WV, WO, Win, Wout,
                                       xb, wqkv, wo, win, wout);

    gemm97<0, 128><<<dim3(24, 32), 256, 0, stream>>>(xb, 1024, wqkv, 1024, 1024,
                                                     nullptr, qkvb, 3072, nullptr, nullptr);
    transpose_v<<<dim3(32, 32), 256, 0, stream>>>(qkvb, vtb);
    attn_stats<<<dim3(32, 32), 256, 0, stream>>>(qkvb, mst);
    attn_av<<<dim3(32, 32), 256, 0, stream>>>(qkvb, vtb, mst, zbuf);
    // attn_out = z @ W_O^T + x  (writes fp32 out fully -> MLP2 atomics can add)
    gemm97<1, 64><<<dim3(16, 32), 256, 0, stream>>>(zbuf, 1024, wo, 1024, 1024,
                                                    out, xmid, 1024, nullptr, x);
    // h = relu(xmid @ W_in^T + b_in)
    gemm97<2, 128><<<dim3(32, 32), 256, 0, stream>>>(xmid, 1024, win, 1024, 1024,
                                                     nullptr, hbuf, 4096, bin, nullptr);
    // out += h @ W_out^T + b_out  (split-K x4, atomic accumulate)
    gemm97<4, 128><<<dim3(8, 32, 4), 256, 0, stream>>>(hbuf, 4096, wout, 4096, 4096,
                                                       out, nullptr, 1024, bout, nullptr);
}

// Round 8
// 436.306 us; speedup vs baseline: 1.0231x; 1.0231x over previous
//
#include <hip/hip_runtime.h>
#include <hip/hip_bf16.h>
#include <cstdint>
#include <cstddef>

typedef __bf16 bf16;
typedef bf16 bf16x4 __attribute__((ext_vector_type(4)));
typedef bf16 bf16x8 __attribute__((ext_vector_type(8)));
typedef float floatx4 __attribute__((ext_vector_type(4)));

#define MFMA16(a, b, c) __builtin_amdgcn_mfma_f32_16x16x32_bf16((a), (b), (c), 0, 0, 0)

// log2(e)/8: S is the RAW k.q dot; softmax uses exp(S/8) = exp2(S*K2)
#define K2 0.18033688011112042f

__device__ __forceinline__ void async16(const void* g, void* l) {
    __builtin_amdgcn_global_load_lds((const __attribute__((address_space(1))) void*)g,
                                     (__attribute__((address_space(3))) void*)l,
                                     16, 0, 0);
}

// swizzled 64x64 bf16 tile stage + reads (attention kernels)
__device__ __forceinline__ void stage64s(const bf16* g0, int ldg, bf16* lds, int wave, int lane) {
#pragma unroll
    for (int i = 0; i < 2; ++i) {
        int r0 = wave * 16 + i * 8;  // wave-uniform
        async16(g0 + (size_t)(r0 + (lane >> 3)) * ldg + ((lane & 7) ^ (lane >> 3)) * 8,
                lds + r0 * 64);
    }
}
__device__ __forceinline__ bf16x8 rd64(const bf16* t, int row, int chunk) {
    return *(const bf16x8*)&t[row * 64 + ((chunk ^ (row & 7)) * 8)];
}
__device__ __forceinline__ bf16x8 rd32(const bf16* t, int row, int quad) {
    return *(const bf16x8*)&t[row * 32 + ((quad ^ (row & 3)) * 8)];
}

// ---------------------------------------------------------------------------
// Fused fp32->bf16 convert
// ---------------------------------------------------------------------------
__global__ __launch_bounds__(256) void cvt_all(const float* __restrict__ x,
                                               const float* __restrict__ WQ,
                                               const float* __restrict__ WK,
                                               const float* __restrict__ WV,
                                               const float* __restrict__ WO,
                                               const float* __restrict__ Win,
                                               const float* __restrict__ Wout,
                                               bf16* __restrict__ xb,
                                               bf16* __restrict__ wqkv,
                                               bf16* __restrict__ wo,
                                               bf16* __restrict__ win,
                                               bf16* __restrict__ wout) {
    int blk = blockIdx.x;
    const float* src;
    bf16* dst;
    int off;
    if (blk < 1024)      { src = WQ;   dst = wqkv;           off = blk; }
    else if (blk < 2048) { src = WK;   dst = wqkv + 1048576; off = blk - 1024; }
    else if (blk < 3072) { src = WV;   dst = wqkv + 2097152; off = blk - 2048; }
    else if (blk < 4096) { src = WO;   dst = wo;             off = blk - 3072; }
    else if (blk < 8192) { src = Win;  dst = win;            off = blk - 4096; }
    else if (blk < 12288){ src = Wout; dst = wout;           off = blk - 8192; }
    else                 { src = x;    dst = xb;             off = blk - 12288; }
    int i = off * 1024 + threadIdx.x * 4;
    float4 v = *(const float4*)(src + i);
    bf16x4 o = {(bf16)v.x, (bf16)v.y, (bf16)v.z, (bf16)v.w};
    *(bf16x4*)(dst + i) = o;
}

// ---------------------------------------------------------------------------
// Epilogue shared by both GEMM templates.
// EPI 0: bf16 store; 1: +res -> fp32+bf16; 2: relu(+bias) -> bf16;
// EPI 3: +bias+Cf -> fp32.
// ---------------------------------------------------------------------------
template <int EPI, int NACC>
__device__ __forceinline__ void epilogue(floatx4 (&acc)[4][NACC], int m0, int n0,
                                         int wm, int wn, int col, int quad,
                                         float* Cf, bf16* Cb, int ldc,
                                         const float* bias, const float* res) {
#pragma unroll
    for (int mi = 0; mi < 4; ++mi)
#pragma unroll
        for (int ni = 0; ni < NACC; ++ni)
#pragma unroll
            for (int r = 0; r < 4; ++r) {
                int row = m0 + wm + mi * 16 + quad * 4 + r;
                int cc = n0 + wn + ni * 16 + col;
                size_t idx = (size_t)row * ldc + cc;
                float v = acc[mi][ni][r];
                if constexpr (EPI == 0) {
                    Cb[idx] = (bf16)v;
                } else if constexpr (EPI == 1) {
                    v += res[idx];
                    Cf[idx] = v;
                    Cb[idx] = (bf16)v;
                } else if constexpr (EPI == 2) {
                    v += bias[cc];
                    v = fmaxf(v, 0.f);
                    Cb[idx] = (bf16)v;
                } else {
                    v += bias[cc] + Cf[idx];
                    Cf[idx] = v;
                }
            }
}

// ---------------------------------------------------------------------------
// gemm_pipe: 128x128 tile, BK=32, 3-stage LDS pipeline, fine vmcnt.
// Best for grids with >=3 blocks/CU (QKV, MLP1).
// ---------------------------------------------------------------------------
template <int EPI>
__global__ __launch_bounds__(256) void gemm_pipe(const bf16* __restrict__ A, int lda,
                                                 const bf16* __restrict__ B, int ldb, int K,
                                                 float* __restrict__ Cf, bf16* __restrict__ Cb,
                                                 int ldc, const float* __restrict__ bias,
                                                 const float* __restrict__ res) {
    __shared__ __align__(16) bf16 As[3][128 * 32];
    __shared__ __align__(16) bf16 Bs[3][128 * 32];
    const int tid = threadIdx.x, wave = tid >> 6, lane = tid & 63;
    const int m0 = blockIdx.y * 128, n0 = blockIdx.x * 128;
    const int wm = (wave >> 1) * 64, wn = (wave & 1) * 64;
    const int col = lane & 15, quad = lane >> 4;
    const int cs8 = ((lane & 3) ^ ((lane >> 2) & 3)) * 8;

    floatx4 acc[4][4];
#pragma unroll
    for (int mi = 0; mi < 4; ++mi)
#pragma unroll
        for (int ni = 0; ni < 4; ++ni) acc[mi][ni] = (floatx4){0.f, 0.f, 0.f, 0.f};

    auto stage = [&](int buf, int k0) {
#pragma unroll
        for (int i = 0; i < 2; ++i) {
            int r0 = wave * 32 + i * 16;
            async16(A + (size_t)(m0 + r0 + (lane >> 2)) * lda + k0 + cs8,
                    As[buf] + r0 * 32);
            async16(B + (size_t)(n0 + r0 + (lane >> 2)) * ldb + k0 + cs8,
                    Bs[buf] + r0 * 32);
        }
    };

    const int nk = K / 32;
    stage(0, 0);
    stage(1, 32);
    for (int it = 0; it < nk; ++it) {
        if (it + 1 < nk) asm volatile("s_waitcnt vmcnt(4)" ::: "memory");
        else             asm volatile("s_waitcnt vmcnt(0)" ::: "memory");
        __builtin_amdgcn_s_barrier();
        if (it + 2 < nk) stage((it + 2) % 3, (it + 2) * 32);

        const bf16* as = As[it % 3];
        const bf16* bs = Bs[it % 3];
        bf16x8 af[4], bfr[4];
#pragma unroll
        for (int mi = 0; mi < 4; ++mi) af[mi] = rd32(as, wm + mi * 16 + col, quad);
#pragma unroll
        for (int ni = 0; ni < 4; ++ni) bfr[ni] = rd32(bs, wn + ni * 16 + col, quad);
#pragma unroll
        for (int mi = 0; mi < 4; ++mi)
#pragma unroll
            for (int ni = 0; ni < 4; ++ni)
                acc[mi][ni] = MFMA16(af[mi], bfr[ni], acc[mi][ni]);
    }
    epilogue<EPI, 4>(acc, m0, n0, wm, wn, col, quad, Cf, Cb, ldc, bias, res);
}

// ---------------------------------------------------------------------------
// gemm_bigk: 128x64 tile, BK=128, single-buffered LDS (48 KB), 2 barriers
// per 128-K chunk -> half the barrier count of BK=64. For the grid-limited
// N=1024 GEMMs (WO, MLP2) stuck at 2 blocks/CU.
// ---------------------------------------------------------------------------
template <int EPI>
__global__ __launch_bounds__(256) void gemm_bigk(const bf16* __restrict__ A, int lda,
                                                 const bf16* __restrict__ B, int ldb, int K,
                                                 float* __restrict__ Cf, bf16* __restrict__ Cb,
                                                 int ldc, const float* __restrict__ bias,
                                                 const float* __restrict__ res) {
    __shared__ __align__(16) bf16 As[128 * 128];
    __shared__ __align__(16) bf16 Bs[64 * 128];
    const int tid = threadIdx.x, wave = tid >> 6, lane = tid & 63;
    const int m0 = blockIdx.y * 128, n0 = blockIdx.x * 64;
    const int wm = (wave >> 1) * 64, wn = (wave & 1) * 32;
    const int col = lane & 15, quad = lane >> 4;

    floatx4 acc[4][2];
#pragma unroll
    for (int mi = 0; mi < 4; ++mi)
#pragma unroll
        for (int ni = 0; ni < 2; ++ni) acc[mi][ni] = (floatx4){0.f, 0.f, 0.f, 0.f};

    // BK=128: 16 lanes per row (16B chunks), 4 rows per instr
    const int rsub = lane >> 4, csub = (lane & 15) * 8;

    for (int k0 = 0; k0 < K; k0 += 128) {
        __syncthreads();
#pragma unroll
        for (int i = 0; i < 8; ++i) {  // A: 128 rows, 4/instr -> 8 per wave
            int r0 = wave * 32 + i * 4;
            async16(A + (size_t)(m0 + r0 + rsub) * lda + k0 + csub, As + r0 * 128);
        }
#pragma unroll
        for (int i = 0; i < 4; ++i) {  // B: 64 rows -> 4 per wave
            int r0 = wave * 16 + i * 4;
            async16(B + (size_t)(n0 + r0 + rsub) * ldb + k0 + csub, Bs + r0 * 128);
        }
        __syncthreads();

#pragma unroll
        for (int ks = 0; ks < 4; ++ks) {
            bf16x8 af[4], bfr[2];
#pragma unroll
            for (int mi = 0; mi < 4; ++mi)
                af[mi] = *(const bf16x8*)&As[(wm + mi * 16 + col) * 128 + ks * 32 + quad * 8];
#pragma unroll
            for (int ni = 0; ni < 2; ++ni)
                bfr[ni] = *(const bf16x8*)&Bs[(wn + ni * 16 + col) * 128 + ks * 32 + quad * 8];
#pragma unroll
            for (int mi = 0; mi < 4; ++mi)
#pragma unroll
                for (int ni = 0; ni < 2; ++ni)
                    acc[mi][ni] = MFMA16(af[mi], bfr[ni], acc[mi][ni]);
        }
    }
    epilogue<EPI, 2>(acc, m0, n0, wm, wn, col, quad, Cf, Cb, ldc, bias, res);
}

// ---------------------------------------------------------------------------
// Transpose V
// ---------------------------------------------------------------------------
__global__ __launch_bounds__(256) void transpose_v(const bf16* __restrict__ qkv,
                                                   bf16* __restrict__ vt) {
    __shared__ bf16 t[64][65];
    const int bh = blockIdx.y, ct = blockIdx.x;
    const int b = bh >> 4, a = bh & 15;
    for (int idx = threadIdx.x; idx < 4096; idx += 256) {
        int c = idx >> 6, h = idx & 63;
        t[h][c] = qkv[(size_t)(b * 2048 + ct * 64 + c) * 3072 + 2048 + a * 64 + h];
    }
    __syncthreads();
    for (int idx = threadIdx.x; idx < 4096; idx += 256) {
        int h = idx >> 6, c = idx & 63;
        vt[(size_t)(bh * 64 + h) * 2048 + ct * 64 + c] = t[h][c];
    }
}

// ---------------------------------------------------------------------------
// Attention pass 1: l_c = sum_{C<=c} exp(S/8). Stores mp2[c] = log2(l_c).
// ---------------------------------------------------------------------------
__global__ __launch_bounds__(256) void attn_stats(const bf16* __restrict__ qkv,
                                                  float* __restrict__ mp2) {
    __shared__ __align__(16) bf16 Kt[64 * 64];
    __shared__ __align__(16) bf16 Qt[3][64 * 64];
    const int xx = blockIdx.x;
    const int ct = (xx & 1) ? (31 - (xx >> 1)) : (xx >> 1);
    const int bh = blockIdx.y;
    const int b = bh >> 4, a = bh & 15;
    const int tid = threadIdx.x, wave = tid >> 6, lane = tid & 63;
    const int col = lane & 15, quad = lane >> 4;
    const bf16* base = qkv + (size_t)b * 2048 * 3072;

    stage64s(base + (size_t)ct * 64 * 3072 + 1024 + a * 64, 3072, Kt, wave, lane);
    stage64s(base + a * 64, 3072, Qt[0], wave, lane);
    if (ct >= 1) stage64s(base + (size_t)1 * 64 * 3072 + a * 64, 3072, Qt[1], wave, lane);

    float lrun[4] = {0.f, 0.f, 0.f, 0.f};
    bf16x8 a0, a1;

    for (int Ct = 0; Ct <= ct; ++Ct) {
        if (Ct < ct) asm volatile("s_waitcnt vmcnt(2)" ::: "memory");
        else         asm volatile("s_waitcnt vmcnt(0)" ::: "memory");
        __builtin_amdgcn_s_barrier();
        if (Ct + 2 <= ct)
            stage64s(base + (size_t)(Ct + 2) * 64 * 3072 + a * 64, 3072,
                     Qt[(Ct + 2) % 3], wave, lane);
        if (Ct == 0) {
            a0 = rd64(Kt, wave * 16 + col, quad);
            a1 = rd64(Kt, wave * 16 + col, quad + 4);
        }
        const bf16* q = Qt[Ct % 3];
#pragma unroll
        for (int nt = 0; nt < 4; ++nt) {
            bf16x8 b0 = rd64(q, nt * 16 + col, quad);
            bf16x8 b1 = rd64(q, nt * 16 + col, quad + 4);
            floatx4 sacc = (floatx4){0.f, 0.f, 0.f, 0.f};
            sacc = MFMA16(a0, b0, sacc);
            sacc = MFMA16(a1, b1, sacc);
#pragma unroll
            for (int r = 0; r < 4; ++r) {
                float e = __builtin_amdgcn_exp2f(sacc[r] * K2);
                if (Ct == ct && (nt * 16 + col) > (wave * 16 + quad * 4 + r)) e = 0.f;
                lrun[r] += e;
            }
        }
    }
#pragma unroll
    for (int r = 0; r < 4; ++r) {
        float t = lrun[r];
        t += __shfl_xor(t, 1);
        t += __shfl_xor(t, 2);
        t += __shfl_xor(t, 4);
        t += __shfl_xor(t, 8);
        lrun[r] = t;
    }
    if (col == 0) {
#pragma unroll
        for (int r = 0; r < 4; ++r) {
            int c = ct * 64 + wave * 16 + quad * 4 + r;
            mp2[(size_t)bh * 2048 + c] = __builtin_amdgcn_logf(lrun[r]);
        }
    }
}

// ---------------------------------------------------------------------------
// Attention pass 2: z[C][h] = sum_{c>=C} P[c][C]*v[c][h]
// ---------------------------------------------------------------------------
__global__ __launch_bounds__(256) void attn_av(const bf16* __restrict__ qkv,
                                               const bf16* __restrict__ vt,
                                               const float* __restrict__ mp2,
                                               bf16* __restrict__ zb) {
    __shared__ __align__(16) bf16 Qt[64 * 64];
    __shared__ __align__(16) bf16 Kt[3][64 * 64];
    __shared__ __align__(16) bf16 Vt[3][64 * 64];
    __shared__ __align__(16) bf16 Pt[64 * 72];
    __shared__ __align__(16) float mpS[2048];
    const int xx = blockIdx.x;
    const int Ctile = (xx & 1) ? (31 - (xx >> 1)) : (xx >> 1);
    const int bh = blockIdx.y;
    const int b = bh >> 4, a = bh & 15;
    const int tid = threadIdx.x, wave = tid >> 6, lane = tid & 63;
    const int col = lane & 15, quad = lane >> 4;
    const bf16* base = qkv + (size_t)b * 2048 * 3072;
    const float* mpb = mp2 + (size_t)bh * 2048;
    const int niter = 32 - Ctile;

    stage64s(base + (size_t)Ctile * 64 * 3072 + a * 64, 3072, Qt, wave, lane);
    {
        int nb = niter * 256;
#pragma unroll
        for (int i = 0; i < 2; ++i) {
            int off = (i * 4 + wave) * 1024;  // wave-uniform
            if (off < nb)
                async16((const char*)(mpb + Ctile * 64) + off + lane * 16,
                        (char*)mpS + off);
        }
    }
    stage64s(base + (size_t)Ctile * 64 * 3072 + 1024 + a * 64, 3072, Kt[0], wave, lane);
    stage64s(vt + (size_t)bh * 64 * 2048 + Ctile * 64, 2048, Vt[0], wave, lane);
    if (niter > 1) {
        stage64s(base + (size_t)(Ctile + 1) * 64 * 3072 + 1024 + a * 64, 3072, Kt[1], wave, lane);
        stage64s(vt + (size_t)bh * 64 * 2048 + (Ctile + 1) * 64, 2048, Vt[1], wave, lane);
    }

    floatx4 zacc[4];
#pragma unroll
    for (int mi = 0; mi < 4; ++mi) zacc[mi] = (floatx4){0.f, 0.f, 0.f, 0.f};
    bf16x8 qf0[4], qf1[4];

    for (int i = 0; i < niter; ++i) {
        const int ct = Ctile + i;
        if (i + 1 < niter) asm volatile("s_waitcnt vmcnt(4)" ::: "memory");
        else               asm volatile("s_waitcnt vmcnt(0)" ::: "memory");
        __builtin_amdgcn_s_barrier();
        if (i + 2 < niter) {
            stage64s(base + (size_t)(ct + 2) * 64 * 3072 + 1024 + a * 64, 3072,
                     Kt[(i + 2) % 3], wave, lane);
            stage64s(vt + (size_t)bh * 64 * 2048 + (ct + 2) * 64, 2048,
                     Vt[(i + 2) % 3], wave, lane);
        }
        if (i == 0) {
#pragma unroll
            for (int nt = 0; nt < 4; ++nt) {
                qf0[nt] = rd64(Qt, nt * 16 + col, quad);
                qf1[nt] = rd64(Qt, nt * 16 + col, quad + 4);
            }
        }
        const bf16* kt = Kt[i % 3];
        const bf16* vts = Vt[i % 3];
        bf16x8 a0 = rd64(kt, wave * 16 + col, quad);
        bf16x8 a1 = rd64(kt, wave * 16 + col, quad + 4);
        float4 mpv = *(const float4*)&mpS[i * 64 + wave * 16 + quad * 4];
        const float mpl[4] = {mpv.x, mpv.y, mpv.z, mpv.w};

#pragma unroll
        for (int nt = 0; nt < 4; ++nt) {
            floatx4 sacc = (floatx4){0.f, 0.f, 0.f, 0.f};
            sacc = MFMA16(a0, qf0[nt], sacc);
            sacc = MFMA16(a1, qf1[nt], sacc);
            bf16x4 pv;
#pragma unroll
            for (int r = 0; r < 4; ++r) {
                float p;
                if (ct == Ctile && (nt * 16 + col) > (wave * 16 + quad * 4 + r))
                    p = 0.f;
                else
                    p = __builtin_amdgcn_exp2f(sacc[r] * K2 - mpl[r]);
                pv[r] = (bf16)p;
            }
            *(bf16x4*)&Pt[(nt * 16 + col) * 72 + wave * 16 + quad * 4] = pv;
        }
        asm volatile("s_waitcnt lgkmcnt(0)" ::: "memory");
        __builtin_amdgcn_s_barrier();

        bf16x8 v0 = rd64(vts, wave * 16 + col, quad);
        bf16x8 v1 = rd64(vts, wave * 16 + col, quad + 4);
#pragma unroll
        for (int mi = 0; mi < 4; ++mi) {
            bf16x8 p0 = *(const bf16x8*)&Pt[(mi * 16 + col) * 72 + quad * 8];
            bf16x8 p1 = *(const bf16x8*)&Pt[(mi * 16 + col) * 72 + 32 + quad * 8];
            zacc[mi] = MFMA16(p0, v0, zacc[mi]);
            zacc[mi] = MFMA16(p1, v1, zacc[mi]);
        }
    }
#pragma unroll
    for (int mi = 0; mi < 4; ++mi)
#pragma unroll
        for (int r = 0; r < 4; ++r) {
            int Cg = Ctile * 64 + mi * 16 + quad * 4 + r;
            zb[(size_t)(b * 2048 + Cg) * 1024 + a * 64 + wave * 16 + col] =
                (bf16)zacc[mi][r];
        }
}

// ---------------------------------------------------------------------------
// Host launcher
// ---------------------------------------------------------------------------
extern "C" void kernel_launch(void* const* d_in, const int* in_sizes, int n_in,
                              void* d_out, int out_size, void* d_ws, size_t ws_size,
                              hipStream_t stream) {
    (void)in_sizes; (void)n_in; (void)out_size; (void)ws_size;
    const float* x    = (const float*)d_in[0];
    const float* WK   = (const float*)d_in[1];
    const float* WQ   = (const float*)d_in[2];
    const float* WV   = (const float*)d_in[3];
    const float* WO   = (const float*)d_in[4];
    const float* Win  = (const float*)d_in[5];
    const float* bin  = (const float*)d_in[6];
    const float* Wout = (const float*)d_in[7];
    const float* bout = (const float*)d_in[8];
    float* out = (float*)d_out;

    char* ws = (char*)d_ws;
    bf16*  xb   = (bf16*)(ws + 0);          //  8 MB
    bf16*  wqkv = (bf16*)(ws + 8388608);    //  6 MB
    bf16*  wo   = (bf16*)(ws + 14680064);   //  2 MB
    bf16*  win  = (bf16*)(ws + 16777216);   //  8 MB
    bf16*  wout = (bf16*)(ws + 25165824);   //  8 MB
    bf16*  qkvb = (bf16*)(ws + 33554432);   // 24 MB
    bf16*  vtb  = (bf16*)(ws + 58720256);   //  8 MB
    float* mst  = (float*)(ws + 67108864);  // 256 KB (mp2)
    bf16*  zbuf = (bf16*)(ws + 67633152);   //  8 MB
    bf16*  xmid = (bf16*)(ws + 76021760);   //  8 MB
    bf16*  hbuf = (bf16*)(ws + 84410368);   // 32 MB

    cvt_all<<<16384, 256, 0, stream>>>(x, WQ, WK, WV, WO, Win, Wout,
                                       xb, wqkv, wo, win, wout);

    // QKV: [4096x1024] x [3072x1024]^T (3 blocks/CU -> pipe)
    gemm_pipe<0><<<dim3(24, 32), 256, 0, stream>>>(xb, 1024, wqkv, 1024, 1024,
                                                   nullptr, qkvb, 3072, nullptr, nullptr);
    transpose_v<<<dim3(32, 32), 256, 0, stream>>>(qkvb, vtb);
    attn_stats<<<dim3(32, 32), 256, 0, stream>>>(qkvb, mst);
    attn_av<<<dim3(32, 32), 256, 0, stream>>>(qkvb, vtb, mst, zbuf);
    // WO: z @ W_O^T + x (2 blocks/CU -> bigk)
    gemm_bigk<1><<<dim3(16, 32), 256, 0, stream>>>(zbuf, 1024, wo, 1024, 1024,
                                                   out, xmid, 1024, nullptr, x);
    // MLP1: relu(xmid @ W_in^T + b_in) (4 blocks/CU -> pipe)
    gemm_pipe<2><<<dim3(32, 32), 256, 0, stream>>>(xmid, 1024, win, 1024, 1024,
                                                   nullptr, hbuf, 4096, bin, nullptr);
    // MLP2: out += h @ W_out^T + b_out (2 blocks/CU -> bigk)
    gemm_bigk<3><<<dim3(16, 32), 256, 0, stream>>>(hbuf, 4096, wout, 4096, 4096,
                                                   out, nullptr, 1024, bout, nullptr);
}

// Round 9
// 397.177 us; speedup vs baseline: 1.1239x; 1.0985x over previous
//
#include <hip/hip_runtime.h>
#include <hip/hip_bf16.h>
#include <cstdint>
#include <cstddef>

typedef __bf16 bf16;
typedef bf16 bf16x4 __attribute__((ext_vector_type(4)));
typedef bf16 bf16x8 __attribute__((ext_vector_type(8)));
typedef float floatx4 __attribute__((ext_vector_type(4)));

#define MFMA16(a, b, c) __builtin_amdgcn_mfma_f32_16x16x32_bf16((a), (b), (c), 0, 0, 0)

// log2(e)/8: S is the RAW k.q dot; softmax uses exp(S/8) = exp2(S*K2)
#define K2 0.18033688011112042f

__device__ __forceinline__ void async16(const void* g, void* l) {
    __builtin_amdgcn_global_load_lds((const __attribute__((address_space(1))) void*)g,
                                     (__attribute__((address_space(3))) void*)l,
                                     16, 0, 0);
}

// swizzled 64x64 bf16 tile stage + reads (attention kernels)
__device__ __forceinline__ void stage64s(const bf16* g0, int ldg, bf16* lds, int wave, int lane) {
#pragma unroll
    for (int i = 0; i < 2; ++i) {
        int r0 = wave * 16 + i * 8;  // wave-uniform
        async16(g0 + (size_t)(r0 + (lane >> 3)) * ldg + ((lane & 7) ^ (lane >> 3)) * 8,
                lds + r0 * 64);
    }
}
__device__ __forceinline__ bf16x8 rd64(const bf16* t, int row, int chunk) {
    return *(const bf16x8*)&t[row * 64 + ((chunk ^ (row & 7)) * 8)];
}
__device__ __forceinline__ bf16x8 rd32(const bf16* t, int row, int quad) {
    return *(const bf16x8*)&t[row * 32 + ((quad ^ (row & 3)) * 8)];
}

// ---------------------------------------------------------------------------
// Fused fp32->bf16 convert
// ---------------------------------------------------------------------------
__global__ __launch_bounds__(256) void cvt_all(const float* __restrict__ x,
                                               const float* __restrict__ WQ,
                                               const float* __restrict__ WK,
                                               const float* __restrict__ WV,
                                               const float* __restrict__ WO,
                                               const float* __restrict__ Win,
                                               const float* __restrict__ Wout,
                                               bf16* __restrict__ xb,
                                               bf16* __restrict__ wqkv,
                                               bf16* __restrict__ wo,
                                               bf16* __restrict__ win,
                                               bf16* __restrict__ wout) {
    int blk = blockIdx.x;
    const float* src;
    bf16* dst;
    int off;
    if (blk < 1024)      { src = WQ;   dst = wqkv;           off = blk; }
    else if (blk < 2048) { src = WK;   dst = wqkv + 1048576; off = blk - 1024; }
    else if (blk < 3072) { src = WV;   dst = wqkv + 2097152; off = blk - 2048; }
    else if (blk < 4096) { src = WO;   dst = wo;             off = blk - 3072; }
    else if (blk < 8192) { src = Win;  dst = win;            off = blk - 4096; }
    else if (blk < 12288){ src = Wout; dst = wout;           off = blk - 8192; }
    else                 { src = x;    dst = xb;             off = blk - 12288; }
    int i = off * 1024 + threadIdx.x * 4;
    float4 v = *(const float4*)(src + i);
    bf16x4 o = {(bf16)v.x, (bf16)v.y, (bf16)v.z, (bf16)v.w};
    *(bf16x4*)(dst + i) = o;
}

// ---------------------------------------------------------------------------
// Epilogue shared by both GEMM templates.
// ---------------------------------------------------------------------------
template <int EPI, int NACC>
__device__ __forceinline__ void epilogue(floatx4 (&acc)[4][NACC], int m0, int n0,
                                         int wm, int wn, int col, int quad,
                                         float* Cf, bf16* Cb, int ldc,
                                         const float* bias, const float* res) {
#pragma unroll
    for (int mi = 0; mi < 4; ++mi)
#pragma unroll
        for (int ni = 0; ni < NACC; ++ni)
#pragma unroll
            for (int r = 0; r < 4; ++r) {
                int row = m0 + wm + mi * 16 + quad * 4 + r;
                int cc = n0 + wn + ni * 16 + col;
                size_t idx = (size_t)row * ldc + cc;
                float v = acc[mi][ni][r];
                if constexpr (EPI == 0) {
                    Cb[idx] = (bf16)v;
                } else if constexpr (EPI == 1) {
                    v += res[idx];
                    Cf[idx] = v;
                    Cb[idx] = (bf16)v;
                } else if constexpr (EPI == 2) {
                    v += bias[cc];
                    v = fmaxf(v, 0.f);
                    Cb[idx] = (bf16)v;
                } else {
                    v += bias[cc] + Cf[idx];
                    Cf[idx] = v;
                }
            }
}

// ---------------------------------------------------------------------------
// gemm_pipe: 128x128 tile, BK=32, 3-stage LDS pipeline, fine vmcnt.
// For grids with >=3 blocks/CU (QKV, MLP1). [R5 best]
// ---------------------------------------------------------------------------
template <int EPI>
__global__ __launch_bounds__(256) void gemm_pipe(const bf16* __restrict__ A, int lda,
                                                 const bf16* __restrict__ B, int ldb, int K,
                                                 float* __restrict__ Cf, bf16* __restrict__ Cb,
                                                 int ldc, const float* __restrict__ bias,
                                                 const float* __restrict__ res) {
    __shared__ __align__(16) bf16 As[3][128 * 32];
    __shared__ __align__(16) bf16 Bs[3][128 * 32];
    const int tid = threadIdx.x, wave = tid >> 6, lane = tid & 63;
    const int m0 = blockIdx.y * 128, n0 = blockIdx.x * 128;
    const int wm = (wave >> 1) * 64, wn = (wave & 1) * 64;
    const int col = lane & 15, quad = lane >> 4;
    const int cs8 = ((lane & 3) ^ ((lane >> 2) & 3)) * 8;

    floatx4 acc[4][4];
#pragma unroll
    for (int mi = 0; mi < 4; ++mi)
#pragma unroll
        for (int ni = 0; ni < 4; ++ni) acc[mi][ni] = (floatx4){0.f, 0.f, 0.f, 0.f};

    auto stage = [&](int buf, int k0) {
#pragma unroll
        for (int i = 0; i < 2; ++i) {
            int r0 = wave * 32 + i * 16;
            async16(A + (size_t)(m0 + r0 + (lane >> 2)) * lda + k0 + cs8,
                    As[buf] + r0 * 32);
            async16(B + (size_t)(n0 + r0 + (lane >> 2)) * ldb + k0 + cs8,
                    Bs[buf] + r0 * 32);
        }
    };

    const int nk = K / 32;
    stage(0, 0);
    stage(1, 32);
    for (int it = 0; it < nk; ++it) {
        if (it + 1 < nk) asm volatile("s_waitcnt vmcnt(4)" ::: "memory");
        else             asm volatile("s_waitcnt vmcnt(0)" ::: "memory");
        __builtin_amdgcn_s_barrier();
        if (it + 2 < nk) stage((it + 2) % 3, (it + 2) * 32);

        const bf16* as = As[it % 3];
        const bf16* bs = Bs[it % 3];
        bf16x8 af[4], bfr[4];
#pragma unroll
        for (int mi = 0; mi < 4; ++mi) af[mi] = rd32(as, wm + mi * 16 + col, quad);
#pragma unroll
        for (int ni = 0; ni < 4; ++ni) bfr[ni] = rd32(bs, wn + ni * 16 + col, quad);
#pragma unroll
        for (int mi = 0; mi < 4; ++mi)
#pragma unroll
            for (int ni = 0; ni < 4; ++ni)
                acc[mi][ni] = MFMA16(af[mi], bfr[ni], acc[mi][ni]);
    }
    epilogue<EPI, 4>(acc, m0, n0, wm, wn, col, quad, Cf, Cb, ldc, bias, res);
}

// ---------------------------------------------------------------------------
// gemm97s: 128x64 tile, BK=64, single-buffered LDS (24 KB), 2 barriers/iter,
// 3-bit XOR chunk swizzle on the 128B rows: LDS[row][c] = G[row][c^(row&7)].
// Fragment reads then spread the 16 col-lanes over all 8 bank groups
// (b128 floor, conflict-free). For the 2-blocks/CU N=1024 GEMMs (WO, MLP2).
// ---------------------------------------------------------------------------
template <int EPI>
__global__ __launch_bounds__(256) void gemm97s(const bf16* __restrict__ A, int lda,
                                               const bf16* __restrict__ B, int ldb, int K,
                                               float* __restrict__ Cf, bf16* __restrict__ Cb,
                                               int ldc, const float* __restrict__ bias,
                                               const float* __restrict__ res) {
    __shared__ __align__(16) bf16 As[128 * 64];
    __shared__ __align__(16) bf16 Bs[64 * 64];
    const int tid = threadIdx.x, wave = tid >> 6, lane = tid & 63;
    const int m0 = blockIdx.y * 128, n0 = blockIdx.x * 64;
    const int wm = (wave >> 1) * 64, wn = (wave & 1) * 32;
    const int col = lane & 15, quad = lane >> 4;

    floatx4 acc[4][2];
#pragma unroll
    for (int mi = 0; mi < 4; ++mi)
#pragma unroll
        for (int ni = 0; ni < 2; ++ni) acc[mi][ni] = (floatx4){0.f, 0.f, 0.f, 0.f};

    // 8 rows per instr, 8 chunks of 16B per 128B row; source chunk XOR row&7
    const int rsub = lane >> 3;
    const int csub = ((lane & 7) ^ rsub) * 8;

    for (int k0 = 0; k0 < K; k0 += 64) {
        __syncthreads();
#pragma unroll
        for (int i = 0; i < 4; ++i) {
            int r0 = wave * 32 + i * 8;  // multiple of 8 -> row&7 = rsub
            async16(A + (size_t)(m0 + r0 + rsub) * lda + k0 + csub, As + r0 * 64);
        }
#pragma unroll
        for (int i = 0; i < 2; ++i) {
            int r0 = wave * 16 + i * 8;
            async16(B + (size_t)(n0 + r0 + rsub) * ldb + k0 + csub, Bs + r0 * 64);
        }
        __syncthreads();

#pragma unroll
        for (int ks = 0; ks < 2; ++ks) {
            bf16x8 af[4], bfr[2];
#pragma unroll
            for (int mi = 0; mi < 4; ++mi) {
                int row = wm + mi * 16 + col;
                af[mi] = *(const bf16x8*)&As[row * 64 + (((ks * 4 + quad) ^ (row & 7)) * 8)];
            }
#pragma unroll
            for (int ni = 0; ni < 2; ++ni) {
                int row = wn + ni * 16 + col;
                bfr[ni] = *(const bf16x8*)&Bs[row * 64 + (((ks * 4 + quad) ^ (row & 7)) * 8)];
            }
#pragma unroll
            for (int mi = 0; mi < 4; ++mi)
#pragma unroll
                for (int ni = 0; ni < 2; ++ni)
                    acc[mi][ni] = MFMA16(af[mi], bfr[ni], acc[mi][ni]);
        }
    }
    epilogue<EPI, 2>(acc, m0, n0, wm, wn, col, quad, Cf, Cb, ldc, bias, res);
}

// ---------------------------------------------------------------------------
// Transpose V
// ---------------------------------------------------------------------------
__global__ __launch_bounds__(256) void transpose_v(const bf16* __restrict__ qkv,
                                                   bf16* __restrict__ vt) {
    __shared__ bf16 t[64][65];
    const int bh = blockIdx.y, ct = blockIdx.x;
    const int b = bh >> 4, a = bh & 15;
    for (int idx = threadIdx.x; idx < 4096; idx += 256) {
        int c = idx >> 6, h = idx & 63;
        t[h][c] = qkv[(size_t)(b * 2048 + ct * 64 + c) * 3072 + 2048 + a * 64 + h];
    }
    __syncthreads();
    for (int idx = threadIdx.x; idx < 4096; idx += 256) {
        int h = idx >> 6, c = idx & 63;
        vt[(size_t)(bh * 64 + h) * 2048 + ct * 64 + c] = t[h][c];
    }
}

// ---------------------------------------------------------------------------
// Attention pass 1: l_c = sum_{C<=c} exp(S/8). Stores mp2[c] = log2(l_c).
// ---------------------------------------------------------------------------
__global__ __launch_bounds__(256) void attn_stats(const bf16* __restrict__ qkv,
                                                  float* __restrict__ mp2) {
    __shared__ __align__(16) bf16 Kt[64 * 64];
    __shared__ __align__(16) bf16 Qt[3][64 * 64];
    const int xx = blockIdx.x;
    const int ct = (xx & 1) ? (31 - (xx >> 1)) : (xx >> 1);
    const int bh = blockIdx.y;
    const int b = bh >> 4, a = bh & 15;
    const int tid = threadIdx.x, wave = tid >> 6, lane = tid & 63;
    const int col = lane & 15, quad = lane >> 4;
    const bf16* base = qkv + (size_t)b * 2048 * 3072;

    stage64s(base + (size_t)ct * 64 * 3072 + 1024 + a * 64, 3072, Kt, wave, lane);
    stage64s(base + a * 64, 3072, Qt[0], wave, lane);
    if (ct >= 1) stage64s(base + (size_t)1 * 64 * 3072 + a * 64, 3072, Qt[1], wave, lane);

    float lrun[4] = {0.f, 0.f, 0.f, 0.f};
    bf16x8 a0, a1;

    for (int Ct = 0; Ct <= ct; ++Ct) {
        if (Ct < ct) asm volatile("s_waitcnt vmcnt(2)" ::: "memory");
        else         asm volatile("s_waitcnt vmcnt(0)" ::: "memory");
        __builtin_amdgcn_s_barrier();
        if (Ct + 2 <= ct)
            stage64s(base + (size_t)(Ct + 2) * 64 * 3072 + a * 64, 3072,
                     Qt[(Ct + 2) % 3], wave, lane);
        if (Ct == 0) {
            a0 = rd64(Kt, wave * 16 + col, quad);
            a1 = rd64(Kt, wave * 16 + col, quad + 4);
        }
        const bf16* q = Qt[Ct % 3];
#pragma unroll
        for (int nt = 0; nt < 4; ++nt) {
            bf16x8 b0 = rd64(q, nt * 16 + col, quad);
            bf16x8 b1 = rd64(q, nt * 16 + col, quad + 4);
            floatx4 sacc = (floatx4){0.f, 0.f, 0.f, 0.f};
            sacc = MFMA16(a0, b0, sacc);
            sacc = MFMA16(a1, b1, sacc);
#pragma unroll
            for (int r = 0; r < 4; ++r) {
                float e = __builtin_amdgcn_exp2f(sacc[r] * K2);
                if (Ct == ct && (nt * 16 + col) > (wave * 16 + quad * 4 + r)) e = 0.f;
                lrun[r] += e;
            }
        }
    }
#pragma unroll
    for (int r = 0; r < 4; ++r) {
        float t = lrun[r];
        t += __shfl_xor(t, 1);
        t += __shfl_xor(t, 2);
        t += __shfl_xor(t, 4);
        t += __shfl_xor(t, 8);
        lrun[r] = t;
    }
    if (col == 0) {
#pragma unroll
        for (int r = 0; r < 4; ++r) {
            int c = ct * 64 + wave * 16 + quad * 4 + r;
            mp2[(size_t)bh * 2048 + c] = __builtin_amdgcn_logf(lrun[r]);
        }
    }
}

// ---------------------------------------------------------------------------
// Attention pass 2: z[C][h] = sum_{c>=C} P[c][C]*v[c][h]
// ---------------------------------------------------------------------------
__global__ __launch_bounds__(256) void attn_av(const bf16* __restrict__ qkv,
                                               const bf16* __restrict__ vt,
                                               const float* __restrict__ mp2,
                                               bf16* __restrict__ zb) {
    __shared__ __align__(16) bf16 Qt[64 * 64];
    __shared__ __align__(16) bf16 Kt[3][64 * 64];
    __shared__ __align__(16) bf16 Vt[3][64 * 64];
    __shared__ __align__(16) bf16 Pt[64 * 72];
    __shared__ __align__(16) float mpS[2048];
    const int xx = blockIdx.x;
    const int Ctile = (xx & 1) ? (31 - (xx >> 1)) : (xx >> 1);
    const int bh = blockIdx.y;
    const int b = bh >> 4, a = bh & 15;
    const int tid = threadIdx.x, wave = tid >> 6, lane = tid & 63;
    const int col = lane & 15, quad = lane >> 4;
    const bf16* base = qkv + (size_t)b * 2048 * 3072;
    const float* mpb = mp2 + (size_t)bh * 2048;
    const int niter = 32 - Ctile;

    stage64s(base + (size_t)Ctile * 64 * 3072 + a * 64, 3072, Qt, wave, lane);
    {
        int nb = niter * 256;
#pragma unroll
        for (int i = 0; i < 2; ++i) {
            int off = (i * 4 + wave) * 1024;  // wave-uniform
            if (off < nb)
                async16((const char*)(mpb + Ctile * 64) + off + lane * 16,
                        (char*)mpS + off);
        }
    }
    stage64s(base + (size_t)Ctile * 64 * 3072 + 1024 + a * 64, 3072, Kt[0], wave, lane);
    stage64s(vt + (size_t)bh * 64 * 2048 + Ctile * 64, 2048, Vt[0], wave, lane);
    if (niter > 1) {
        stage64s(base + (size_t)(Ctile + 1) * 64 * 3072 + 1024 + a * 64, 3072, Kt[1], wave, lane);
        stage64s(vt + (size_t)bh * 64 * 2048 + (Ctile + 1) * 64, 2048, Vt[1], wave, lane);
    }

    floatx4 zacc[4];
#pragma unroll
    for (int mi = 0; mi < 4; ++mi) zacc[mi] = (floatx4){0.f, 0.f, 0.f, 0.f};
    bf16x8 qf0[4], qf1[4];

    for (int i = 0; i < niter; ++i) {
        const int ct = Ctile + i;
        if (i + 1 < niter) asm volatile("s_waitcnt vmcnt(4)" ::: "memory");
        else               asm volatile("s_waitcnt vmcnt(0)" ::: "memory");
        __builtin_amdgcn_s_barrier();
        if (i + 2 < niter) {
            stage64s(base + (size_t)(ct + 2) * 64 * 3072 + 1024 + a * 64, 3072,
                     Kt[(i + 2) % 3], wave, lane);
            stage64s(vt + (size_t)bh * 64 * 2048 + (ct + 2) * 64, 2048,
                     Vt[(i + 2) % 3], wave, lane);
        }
        if (i == 0) {
#pragma unroll
            for (int nt = 0; nt < 4; ++nt) {
                qf0[nt] = rd64(Qt, nt * 16 + col, quad);
                qf1[nt] = rd64(Qt, nt * 16 + col, quad + 4);
            }
        }
        const bf16* kt = Kt[i % 3];
        const bf16* vts = Vt[i % 3];
        bf16x8 a0 = rd64(kt, wave * 16 + col, quad);
        bf16x8 a1 = rd64(kt, wave * 16 + col, quad + 4);
        float4 mpv = *(const float4*)&mpS[i * 64 + wave * 16 + quad * 4];
        const float mpl[4] = {mpv.x, mpv.y, mpv.z, mpv.w};

#pragma unroll
        for (int nt = 0; nt < 4; ++nt) {
            floatx4 sacc = (floatx4){0.f, 0.f, 0.f, 0.f};
            sacc = MFMA16(a0, qf0[nt], sacc);
            sacc = MFMA16(a1, qf1[nt], sacc);
            bf16x4 pv;
#pragma unroll
            for (int r = 0; r < 4; ++r) {
                float p;
                if (ct == Ctile && (nt * 16 + col) > (wave * 16 + quad * 4 + r))
                    p = 0.f;
                else
                    p = __builtin_amdgcn_exp2f(sacc[r] * K2 - mpl[r]);
                pv[r] = (bf16)p;
            }
            *(bf16x4*)&Pt[(nt * 16 + col) * 72 + wave * 16 + quad * 4] = pv;
        }
        asm volatile("s_waitcnt lgkmcnt(0)" ::: "memory");
        __builtin_amdgcn_s_barrier();

        bf16x8 v0 = rd64(vts, wave * 16 + col, quad);
        bf16x8 v1 = rd64(vts, wave * 16 + col, quad + 4);
#pragma unroll
        for (int mi = 0; mi < 4; ++mi) {
            bf16x8 p0 = *(const bf16x8*)&Pt[(mi * 16 + col) * 72 + quad * 8];
            bf16x8 p1 = *(const bf16x8*)&Pt[(mi * 16 + col) * 72 + 32 + quad * 8];
            zacc[mi] = MFMA16(p0, v0, zacc[mi]);
            zacc[mi] = MFMA16(p1, v1, zacc[mi]);
        }
    }
#pragma unroll
    for (int mi = 0; mi < 4; ++mi)
#pragma unroll
        for (int r = 0; r < 4; ++r) {
            int Cg = Ctile * 64 + mi * 16 + quad * 4 + r;
            zb[(size_t)(b * 2048 + Cg) * 1024 + a * 64 + wave * 16 + col] =
                (bf16)zacc[mi][r];
        }
}

// ---------------------------------------------------------------------------
// Host launcher
// ---------------------------------------------------------------------------
extern "C" void kernel_launch(void* const* d_in, const int* in_sizes, int n_in,
                              void* d_out, int out_size, void* d_ws, size_t ws_size,
                              hipStream_t stream) {
    (void)in_sizes; (void)n_in; (void)out_size; (void)ws_size;
    const float* x    = (const float*)d_in[0];
    const float* WK   = (const float*)d_in[1];
    const float* WQ   = (const float*)d_in[2];
    const float* WV   = (const float*)d_in[3];
    const float* WO   = (const float*)d_in[4];
    const float* Win  = (const float*)d_in[5];
    const float* bin  = (const float*)d_in[6];
    const float* Wout = (const float*)d_in[7];
    const float* bout = (const float*)d_in[8];
    float* out = (float*)d_out;

    char* ws = (char*)d_ws;
    bf16*  xb   = (bf16*)(ws + 0);          //  8 MB
    bf16*  wqkv = (bf16*)(ws + 8388608);    //  6 MB
    bf16*  wo   = (bf16*)(ws + 14680064);   //  2 MB
    bf16*  win  = (bf16*)(ws + 16777216);   //  8 MB
    bf16*  wout = (bf16*)(ws + 25165824);   //  8 MB
    bf16*  qkvb = (bf16*)(ws + 33554432);   // 24 MB
    bf16*  vtb  = (bf16*)(ws + 58720256);   //  8 MB
    float* mst  = (float*)(ws + 67108864);  // 256 KB (mp2)
    bf16*  zbuf = (bf16*)(ws + 67633152);   //  8 MB
    bf16*  xmid = (bf16*)(ws + 76021760);   //  8 MB
    bf16*  hbuf = (bf16*)(ws + 84410368);   // 32 MB

    cvt_all<<<16384, 256, 0, stream>>>(x, WQ, WK, WV, WO, Win, Wout,
                                       xb, wqkv, wo, win, wout);

    // QKV: [4096x1024] x [3072x1024]^T (3 blocks/CU -> pipe)
    gemm_pipe<0><<<dim3(24, 32), 256, 0, stream>>>(xb, 1024, wqkv, 1024, 1024,
                                                   nullptr, qkvb, 3072, nullptr, nullptr);
    transpose_v<<<dim3(32, 32), 256, 0, stream>>>(qkvb, vtb);
    attn_stats<<<dim3(32, 32), 256, 0, stream>>>(qkvb, mst);
    attn_av<<<dim3(32, 32), 256, 0, stream>>>(qkvb, vtb, mst, zbuf);
    // WO: z @ W_O^T + x (2 blocks/CU -> swizzled BK=64)
    gemm97s<1><<<dim3(16, 32), 256, 0, stream>>>(zbuf, 1024, wo, 1024, 1024,
                                                 out, xmid, 1024, nullptr, x);
    // MLP1: relu(xmid @ W_in^T + b_in) (4 blocks/CU -> pipe)
    gemm_pipe<2><<<dim3(32, 32), 256, 0, stream>>>(xmid, 1024, win, 1024, 1024,
                                                   nullptr, hbuf, 4096, bin, nullptr);
    // MLP2: out += h @ W_out^T + b_out (2 blocks/CU -> swizzled BK=64)
    gemm97s<3><<<dim3(16, 32), 256, 0, stream>>>(hbuf, 4096, wout, 4096, 4096,
                                                 out, nullptr, 1024, bout, nullptr);
}